// Round 16
// baseline (107.724 us; speedup 1.0000x reference)
//
#include <hip/hip_runtime.h>
#include <cstdint>
#include <cstddef>

typedef __bf16 bf16;
typedef __bf16 bf16x8 __attribute__((ext_vector_type(8)));
typedef __bf16 bf16x4 __attribute__((ext_vector_type(4)));
typedef float  f32x4  __attribute__((ext_vector_type(4)));
typedef float  f32x16 __attribute__((ext_vector_type(16)));

constexpr int Bb  = 2;
constexpr int Ss  = 2048;
constexpr int Hh  = 768;
constexpr int NHh = 12;
constexpr int DHh = 64;
constexpr int Mm  = Bb * Ss;   // 4096
constexpr int N3  = 3 * Hh;    // 2304
constexpr int QKW = 2 * Hh;    // 1536

__device__ __forceinline__ float fexp2(float x) { return __builtin_amdgcn_exp2f(x); }

__device__ __forceinline__ void gload_lds16(void* lds, const void* g) {
  __builtin_amdgcn_global_load_lds(
      (__attribute__((address_space(1))) void*)(uintptr_t)g,
      (__attribute__((address_space(3))) void*)(uint32_t)(uintptr_t)lds,
      16, 0, 0);
}

// compiler-only memory fence: emits nothing, pins memory-op ordering (r12-proven)
__device__ __forceinline__ void cfence() { asm volatile("" ::: "memory"); }

// single kernel converts all three f32 inputs to bf16
__global__ void cvt3_f32_bf16(const float* __restrict__ x,  bf16* __restrict__ xb,
                              const float* __restrict__ w1, bf16* __restrict__ w1b,
                              const float* __restrict__ w2, bf16* __restrict__ w2b) {
  const int st = gridDim.x * blockDim.x;
  int i0 = blockIdx.x * blockDim.x + threadIdx.x;
  for (int i = i0; i < 786432; i += st) {
    float4 v = ((const float4*)x)[i];
    bf16x4 o; o[0]=(bf16)v.x; o[1]=(bf16)v.y; o[2]=(bf16)v.z; o[3]=(bf16)v.w;
    ((bf16x4*)xb)[i] = o;
  }
  for (int i = i0; i < 442368; i += st) {
    float4 v = ((const float4*)w1)[i];
    bf16x4 o; o[0]=(bf16)v.x; o[1]=(bf16)v.y; o[2]=(bf16)v.z; o[3]=(bf16)v.w;
    ((bf16x4*)w1b)[i] = o;
  }
  for (int i = i0; i < 147456; i += st) {
    float4 v = ((const float4*)w2)[i];
    bf16x4 o; o[0]=(bf16)v.x; o[1]=(bf16)v.y; o[2]=(bf16)v.z; o[3]=(bf16)v.w;
    ((bf16x4*)w2b)[i] = o;
  }
}

// C = A[M,768] * Bw[N,768]^T, tile BM x 128, double-buffered LDS, 1 barrier/iter.
// 1D grid, XCD-swizzled m-chunked (T1, r15-proven). NXT = N/128 tiles.
// OUTMODE 0 (BM=128): Q -> row-major [4096][768]; K -> Kfrag, V -> Vfrag
// (MFMA-A-fragment order, proven r9/r13). OUTMODE 1: f32 out + bias.
template<int OUTMODE, int BM, int NXT>
__global__ __launch_bounds__(256, 3)
void gemm_bt(const bf16* __restrict__ A, const bf16* __restrict__ Bw,
             bf16* __restrict__ Qb, bf16* __restrict__ Kf, bf16* __restrict__ Vf,
             float* __restrict__ Cf, const float* __restrict__ bias)
{
  constexpr int K = 768;
  constexpr int NT = K / 32;
  constexpr int MI = BM / 32;
  constexpr int ABUF = BM * 64;
  __shared__ bf16 As[2][BM * 32];
  __shared__ bf16 Bs[2][128 * 32];
  const int tid  = threadIdx.x;
  const int wid  = tid >> 6, lane = tid & 63;
  const int lr   = lane & 15, lk = lane >> 4;

  const int id   = blockIdx.x;
  const int swz  = (id & 7) * (gridDim.x >> 3) + (id >> 3);
  const int n0   = (swz % NXT) * 128;
  const int m0   = (swz / NXT) * BM;
  const int wm   = (wid >> 1) * (BM / 2), wn = (wid & 1) * 64;

  f32x4 acc[MI][4] = {};

  const char* Ag = (const char*)(A  + (size_t)m0 * K) + (size_t)(tid >> 2) * (K * 2) + (tid & 3) * 16;
  const char* Bg = (const char*)(Bw + (size_t)n0 * K) + (size_t)(tid >> 2) * (K * 2) + (tid & 3) * 16;
  constexpr size_t rstep = (size_t)64 * K * 2;

  auto stage = [&](int buf, int kb) {
    char* aw = (char*)As + buf * ABUF + wid * 1024;
    char* bw = (char*)Bs + buf * 8192 + wid * 1024;
    gload_lds16(aw, Ag + (size_t)kb * 2);
    if constexpr (BM == 128)
      gload_lds16(aw + 4096, Ag + rstep + (size_t)kb * 2);
    gload_lds16(bw,        Bg + (size_t)kb * 2);
    gload_lds16(bw + 4096, Bg + rstep + (size_t)kb * 2);
  };

  stage(0, 0);
  asm volatile("s_waitcnt vmcnt(0)" ::: "memory");
  __syncthreads();

#pragma unroll 1
  for (int t = 0; t < NT; ++t) {
    const int cur = t & 1;
    if (t + 1 < NT) stage(cur ^ 1, (t + 1) * 32);
    __builtin_amdgcn_sched_barrier(0);

    bf16x8 af[MI], bfv[4];
#pragma unroll
    for (int i = 0; i < MI; ++i)
      af[i]  = *(const bf16x8*)((const char*)As + cur * ABUF + ((wm + i * 16 + lr) * 32 + lk * 8) * 2);
#pragma unroll
    for (int j = 0; j < 4; ++j)
      bfv[j] = *(const bf16x8*)((const char*)Bs + cur * 8192 + ((wn + j * 16 + lr) * 32 + lk * 8) * 2);
#pragma unroll
    for (int i = 0; i < MI; ++i)
#pragma unroll
      for (int j = 0; j < 4; ++j)
        acc[i][j] = __builtin_amdgcn_mfma_f32_16x16x32_bf16(af[i], bfv[j], acc[i][j], 0, 0, 0);

    __syncthreads();
  }

  if constexpr (OUTMODE == 1) {
#pragma unroll
    for (int i = 0; i < MI; ++i)
#pragma unroll
      for (int j = 0; j < 4; ++j) {
        const int n = n0 + wn + j * 16 + lr;
        const float bv = bias[n];
#pragma unroll
        for (int r = 0; r < 4; ++r) {
          const int m = m0 + wm + i * 16 + lk * 4 + r;
          Cf[(size_t)m * Hh + n] = acc[i][j][r] + bv;
        }
      }
  } else {
    const int bidx = m0 >> 11;
    const int kvb  = (m0 & 2047) + wm + lk * 4;
    if (n0 < Hh) {                 // Q -> row-major
#pragma unroll
      for (int i = 0; i < MI; ++i)
#pragma unroll
        for (int j = 0; j < 4; ++j) {
          const int n = n0 + wn + j * 16 + lr;
#pragma unroll
          for (int r = 0; r < 4; ++r) {
            const int m = m0 + wm + i * 16 + lk * 4 + r;
            Qb[(size_t)m * Hh + n] = (bf16)acc[i][j][r];
          }
        }
    } else if (n0 < QKW) {         // K -> Kfrag
#pragma unroll
      for (int i = 0; i < MI; ++i)
#pragma unroll
        for (int j = 0; j < 4; ++j) {
          const int colv = (n0 - Hh) + wn + j * 16 + lr;
          const int hh = colv >> 6, dd = colv & 63;
          bf16* kfh = Kf + (size_t)(bidx * NHh + hh) * 131072;
#pragma unroll
          for (int r = 0; r < 4; ++r) {
            const int kv = kvb + i * 16 + r;
            const size_t idx = (size_t)((((kv >> 5) * 4 + (dd >> 4)) * 64
                                + ((dd >> 3) & 1) * 32 + (kv & 31)) * 8 + (dd & 7));
            kfh[idx] = (bf16)acc[i][j][r];
          }
        }
    } else {                       // V -> Vfrag
#pragma unroll
      for (int i = 0; i < MI; ++i)
#pragma unroll
        for (int j = 0; j < 4; ++j) {
          const int colv = (n0 - QKW) + wn + j * 16 + lr;
          const int hh = colv >> 6, dd = colv & 63;
          const int bh = bidx * NHh + hh;
          const int mb = kvb + i * 16;
          bf16x4 pv;
#pragma unroll
          for (int r = 0; r < 4; ++r) pv[r] = (bf16)acc[i][j][r];
          const size_t idx8 = (((size_t)bh * 128 + (mb >> 4)) * 2 + (dd >> 5)) * 64
                              + ((mb >> 3) & 1) * 32 + (dd & 31);
          *(bf16x4*)(Vf + idx8 * 8 + (mb & 7)) = pv;
        }
    }
  }
}

// Flash attention v12: grid 1536 (24 bh x 64 q-tiles of 32 rows), 256 thr,
// 4 waves = 4 DISJOINT kv-quarters (512 kv, 8 iters). Barrier-free main loop,
// step() verbatim from r9's PASSING kernel (K reg-double-buffered, V single-
// buffered, compiler auto-waitcnt only). VALU row-sum (r8-proven). 4-way LDS
// merge. launch_bounds(256,3): NO register squeeze (r10's only bad delta).
// 6 blocks/CU (24 waves/CU) vs r13's 3 -- 2x latency-hiding TLP.
__global__ __launch_bounds__(256, 3)
void attn_fwd12(const bf16* __restrict__ Qb, const bf16* __restrict__ Kfrag,
                const bf16* __restrict__ Vfrag, bf16* __restrict__ aout)
{
  __shared__ __align__(16) char lds[25088];   // merge only: 3 x 8320
  const int tid  = threadIdx.x;
  const int grp  = tid >> 6, lane = tid & 63;
  const int lq   = lane & 31, hi = lane >> 5;

  // XCD swizzle: 1536 blocks, 192/XCD -> 3 heads per XCD (L2-resident K/V)
  const int orig = blockIdx.x;
  const int swz  = (orig & 7) * 192 + (orig >> 3);
  const int qt   = swz & 63;
  const int bh   = swz >> 6;
  const int b    = bh / NHh, h = bh % NHh;
  const int q0   = qt * 32;

  constexpr float Cs = 0.18033688011112042f;  // 0.125 * log2(e)
  const bf16* qrow = Qb + (size_t)(b * Ss + q0 + lq) * Hh + h * DHh;
  bf16x8 qf[4];
#pragma unroll
  for (int j = 0; j < 4; ++j) {
    bf16x8 t = *(const bf16x8*)(qrow + j * 16 + hi * 8);
#pragma unroll
    for (int e = 0; e < 8; ++e) t[e] = (bf16)((float)t[e] * Cs);
    qf[j] = t;
  }

  // per-wave disjoint kv-quarter (512 kv = 65536 B of frag data each)
  const char* Kfp = (const char*)Kfrag + (size_t)bh * 262144 + grp * 65536 + lane * 16;
  const char* Vfp = (const char*)Vfrag + (size_t)bh * 262144 + grp * 65536 + lane * 16;

  f32x16 oacc[2] = {};
  float rsum = 0.f;
  bf16x8 kfA[2][4], kfB[2][4], vf[4][2];

  // prologue: K(0) -> kfA, V(0) -> vf (auto-waitcnt gates uses)
#pragma unroll
  for (int kvc = 0; kvc < 2; ++kvc)
#pragma unroll
    for (int j = 0; j < 4; ++j)
      kfA[kvc][j] = *(const bf16x8*)(Kfp + kvc * 4096 + j * 1024);
#pragma unroll
  for (int s4 = 0; s4 < 4; ++s4)
#pragma unroll
    for (int dc = 0; dc < 2; ++dc)
      vf[s4][dc] = *(const bf16x8*)(Vfp + (s4 * 2 + dc) * 1024);

  auto step = [&](bf16x8 (&KC)[2][4], bf16x8 (&KN)[2][4], int i) {
    // QK^T kvc0 (auto-waitcnt gates on KC regs)
    f32x16 s0 = {};
    __builtin_amdgcn_s_setprio(1);
#pragma unroll
    for (int j = 0; j < 4; ++j)
      s0 = __builtin_amdgcn_mfma_f32_32x32x16_bf16(KC[0][j], qf[j], s0, 0, 0, 0);
    __builtin_amdgcn_s_setprio(0);

    // softmax half 0
    uint32_t w0[8];
    float rp0 = 0.f, rp1 = 0.f;
#pragma unroll
    for (int m = 0; m < 8; ++m) {
      const float e0 = fexp2(s0[2 * m]);
      const float e1 = fexp2(s0[2 * m + 1]);
      rp0 += e0; rp1 += e1;
      union { bf16 hh[2]; uint32_t u; } cv;
      cv.hh[0] = (bf16)e0; cv.hh[1] = (bf16)e1;
      w0[m] = cv.u;
    }

    // QK^T kvc1
    f32x16 s1 = {};
    __builtin_amdgcn_s_setprio(1);
#pragma unroll
    for (int j = 0; j < 4; ++j)
      s1 = __builtin_amdgcn_mfma_f32_32x32x16_bf16(KC[1][j], qf[j], s1, 0, 0, 0);
    __builtin_amdgcn_s_setprio(0);

    // issue K(i+1) -> KN (full softmax+PV window before next-iter use)
    __builtin_amdgcn_sched_barrier(0);
    {
      const char* kp = Kfp + (size_t)(((i + 1) & 7) * 8192);
#pragma unroll
      for (int kvc = 0; kvc < 2; ++kvc)
#pragma unroll
        for (int j = 0; j < 4; ++j)
          KN[kvc][j] = *(const bf16x8*)(kp + kvc * 4096 + j * 1024);
    }
    __builtin_amdgcn_sched_barrier(0);

    // softmax half 1
    uint32_t w1[8];
#pragma unroll
    for (int m = 0; m < 8; ++m) {
      const float e0 = fexp2(s1[2 * m]);
      const float e1 = fexp2(s1[2 * m + 1]);
      rp0 += e0; rp1 += e1;
      union { bf16 hh[2]; uint32_t u; } cv;
      cv.hh[0] = (bf16)e0; cv.hh[1] = (bf16)e1;
      w1[m] = cv.u;
    }
    rsum += rp0 + rp1;

    // PV (auto-waitcnt gates on vf regs)
    __builtin_amdgcn_s_setprio(1);
#pragma unroll
    for (int s4 = 0; s4 < 4; ++s4) {
      const int sb = s4 & 1;
      const uint32_t* wp = (s4 < 2) ? w0 : w1;
      uint32_t a0 = wp[4 * sb + 0], b0 = wp[4 * sb + 2];
      uint32_t a1 = wp[4 * sb + 1], b1 = wp[4 * sb + 3];
      asm("v_permlane32_swap_b32 %0, %1" : "+v"(a0), "+v"(b0));
      asm("v_permlane32_swap_b32 %0, %1" : "+v"(a1), "+v"(b1));
      union { uint32_t u[4]; bf16x8 v; } pf;
      pf.u[0] = a0; pf.u[1] = a1; pf.u[2] = b0; pf.u[3] = b1;
#pragma unroll
      for (int dc = 0; dc < 2; ++dc)
        oacc[dc] = __builtin_amdgcn_mfma_f32_32x32x16_bf16(vf[s4][dc], pf.v, oacc[dc], 0, 0, 0);
    }
    __builtin_amdgcn_s_setprio(0);

    // issue V(i+1) -> vf (WAR on vf keeps this after PV reads)
    __builtin_amdgcn_sched_barrier(0);
    {
      const char* vp = Vfp + (size_t)(((i + 1) & 7) * 8192);
#pragma unroll
      for (int s4 = 0; s4 < 4; ++s4)
#pragma unroll
        for (int dc = 0; dc < 2; ++dc)
          vf[s4][dc] = *(const bf16x8*)(vp + (s4 * 2 + dc) * 1024);
    }
    __builtin_amdgcn_sched_barrier(0);
  };

#pragma unroll 1
  for (int ii = 0; ii < 4; ++ii) {
    step(kfA, kfB, 2 * ii);
    step(kfB, kfA, 2 * ii + 1);
  }

  rsum += __shfl_xor(rsum, 32, 64);   // combine hi-half partials -> quarter-sum

  // 4-way merge: grps 1..3 export (O, rsum) via LDS; grp 0 combines + writes
  if (grp != 0) {
    char* mb = lds + (grp - 1) * 8320;
#pragma unroll
    for (int dc = 0; dc < 2; ++dc)
#pragma unroll
      for (int rr = 0; rr < 4; ++rr) {
        f32x4 t;
#pragma unroll
        for (int e = 0; e < 4; ++e) t[e] = oacc[dc][rr * 4 + e];
        *(f32x4*)(mb + lane * 128 + (dc * 4 + rr) * 16) = t;
      }
    if (lane < 32) *(float*)(mb + 8192 + lane * 4) = rsum;
  }
  __syncthreads();
  if (grp == 0) {
    float lt = rsum;
#pragma unroll
    for (int g = 0; g < 3; ++g) {
      const char* mb = lds + g * 8320;
      lt += *(const float*)(mb + 8192 + lq * 4);
#pragma unroll
      for (int dc = 0; dc < 2; ++dc)
#pragma unroll
        for (int rr = 0; rr < 4; ++rr) {
          const f32x4 o2 = *(const f32x4*)(mb + lane * 128 + (dc * 4 + rr) * 16);
#pragma unroll
          for (int e = 0; e < 4; ++e) oacc[dc][rr * 4 + e] += o2[e];
        }
    }
    const float linv = 1.0f / lt;
    bf16* orow = aout + (size_t)(b * Ss + q0 + lq) * Hh + h * DHh;
#pragma unroll
    for (int dc = 0; dc < 2; ++dc)
#pragma unroll
      for (int rr = 0; rr < 4; ++rr) {
        bf16x4 ov;
#pragma unroll
        for (int e = 0; e < 4; ++e)
          ov[e] = (bf16)(oacc[dc][rr * 4 + e] * linv);
        *(bf16x4*)(orow + dc * 32 + rr * 8 + hi * 4) = ov;
      }
  }
}

extern "C" void kernel_launch(void* const* d_in, const int* in_sizes, int n_in,
                              void* d_out, int out_size, void* d_ws, size_t ws_size,
                              hipStream_t stream) {
  const float* x     = (const float*)d_in[0];
  const float* w_qkv = (const float*)d_in[1];
  const float* w_out = (const float*)d_in[2];
  const float* b_out = (const float*)d_in[3];
  char* ws = (char*)d_ws;
  bf16* xb    = (bf16*)(ws + 0);
  bf16* wqkvb = (bf16*)(ws + 6291456);
  bf16* woutb = (bf16*)(ws + 9830400);
  bf16* Qb    = (bf16*)(ws + 11010048);
  bf16* Kfrag = (bf16*)(ws + 17301504);
  bf16* Vfrag = (bf16*)(ws + 23592960);
  bf16* aoutb = (bf16*)(ws + 29884416);

  cvt3_f32_bf16<<<2048, 256, 0, stream>>>(x, xb, w_qkv, wqkvb, w_out, woutb);

  gemm_bt<0, 128, 18><<<576, 256, 0, stream>>>(xb, wqkvb, Qb, Kfrag, Vfrag,
                                               nullptr, nullptr);
  attn_fwd12<<<1536, 256, 0, stream>>>(Qb, Kfrag, Vfrag, aoutb);
  gemm_bt<1, 64, 6><<<384, 256, 0, stream>>>(aoutb, woutb, nullptr, nullptr, nullptr,
                                             (float*)d_out, b_out);
}

// Round 17
// 93.284 us; speedup vs baseline: 1.1548x; 1.1548x over previous
//
#include <hip/hip_runtime.h>
#include <cstdint>
#include <cstddef>

typedef __bf16 bf16;
typedef __bf16 bf16x8 __attribute__((ext_vector_type(8)));
typedef __bf16 bf16x4 __attribute__((ext_vector_type(4)));
typedef float  f32x4  __attribute__((ext_vector_type(4)));
typedef float  f32x8  __attribute__((ext_vector_type(8)));
typedef float  f32x16 __attribute__((ext_vector_type(16)));

constexpr int Bb  = 2;
constexpr int Ss  = 2048;
constexpr int Hh  = 768;
constexpr int NHh = 12;
constexpr int DHh = 64;
constexpr int Mm  = Bb * Ss;   // 4096
constexpr int N3  = 3 * Hh;    // 2304
constexpr int QKW = 2 * Hh;    // 1536

__device__ __forceinline__ float fexp2(float x) { return __builtin_amdgcn_exp2f(x); }

__device__ __forceinline__ void gload_lds16(void* lds, const void* g) {
  __builtin_amdgcn_global_load_lds(
      (__attribute__((address_space(1))) void*)(uintptr_t)g,
      (__attribute__((address_space(3))) void*)(uint32_t)(uintptr_t)lds,
      16, 0, 0);
}

// compiler-only memory fence: emits nothing, pins memory-op ordering (r12-proven)
__device__ __forceinline__ void cfence() { asm volatile("" ::: "memory"); }

// converts the two weight matrices to bf16 (x is consumed as f32 by GEMM1)
__global__ void cvt2_f32_bf16(const float* __restrict__ w1, bf16* __restrict__ w1b,
                              const float* __restrict__ w2, bf16* __restrict__ w2b) {
  const int st = gridDim.x * blockDim.x;
  int i0 = blockIdx.x * blockDim.x + threadIdx.x;
  for (int i = i0; i < 442368; i += st) {       // w_qkv: 2304*768/4
    float4 v = ((const float4*)w1)[i];
    bf16x4 o; o[0]=(bf16)v.x; o[1]=(bf16)v.y; o[2]=(bf16)v.z; o[3]=(bf16)v.w;
    ((bf16x4*)w1b)[i] = o;
  }
  for (int i = i0; i < 147456; i += st) {       // w_out: 768*768/4
    float4 v = ((const float4*)w2)[i];
    bf16x4 o; o[0]=(bf16)v.x; o[1]=(bf16)v.y; o[2]=(bf16)v.z; o[3]=(bf16)v.w;
    ((bf16x4*)w2b)[i] = o;
  }
}

// C = A[M,768] * Bw[N,768]^T, tile BM x 128, double-buffered LDS, 1 barrier/iter.
// 1D grid, XCD-swizzled m-chunked (T1, r15-proven). NXT = N/128 tiles.
// AF32: A is read as f32 and converted to bf16 at fragment load (fuses cvt of x).
// OUTMODE 0 (BM=128): Q -> row-major [4096][768]; K -> Kfrag, V -> Vfrag
// (MFMA-A-fragment order, proven r9/r13). OUTMODE 1: f32 out + bias.
template<int OUTMODE, int BM, int NXT, int AF32>
__global__ __launch_bounds__(256, 3)
void gemm_bt(const bf16* __restrict__ A, const bf16* __restrict__ Bw,
             bf16* __restrict__ Qb, bf16* __restrict__ Kf, bf16* __restrict__ Vf,
             float* __restrict__ Cf, const float* __restrict__ bias)
{
  constexpr int K = 768;
  constexpr int NT = K / 32;
  constexpr int MI = BM / 32;
  constexpr int ABUF = AF32 ? BM * 128 : BM * 64;   // bytes per A buffer
  __shared__ __align__(16) char AsB[2 * ABUF];
  __shared__ __align__(16) char BsB[2 * 8192];
  const int tid  = threadIdx.x;
  const int wid  = tid >> 6, lane = tid & 63;
  const int lr   = lane & 15, lk = lane >> 4;

  const int id   = blockIdx.x;
  const int swz  = (id & 7) * (gridDim.x >> 3) + (id >> 3);
  const int n0   = (swz % NXT) * 128;
  const int m0   = (swz / NXT) * BM;
  const int wm   = (wid >> 1) * (BM / 2), wn = (wid & 1) * 64;

  f32x4 acc[MI][4] = {};

  const char* Ag = AF32
    ? (const char*)A + (size_t)m0 * K * 4 + (size_t)(tid >> 3) * (K * 4) + (tid & 7) * 16
    : (const char*)A + (size_t)m0 * K * 2 + (size_t)(tid >> 2) * (K * 2) + (tid & 3) * 16;
  const char* Bg = (const char*)(Bw + (size_t)n0 * K) + (size_t)(tid >> 2) * (K * 2) + (tid & 3) * 16;
  constexpr size_t rstep = (size_t)64 * K * 2;

  auto stage = [&](int buf, int kb) {
    char* aw = AsB + buf * ABUF + wid * 1024;
    char* bw = BsB + buf * 8192 + wid * 1024;
    if constexpr (AF32) {
#pragma unroll
      for (int j = 0; j < 4; ++j)
        gload_lds16(aw + j * 4096, Ag + (size_t)j * 32 * K * 4 + (size_t)kb * 4);
    } else {
      gload_lds16(aw, Ag + (size_t)kb * 2);
      if constexpr (BM == 128)
        gload_lds16(aw + 4096, Ag + rstep + (size_t)kb * 2);
    }
    gload_lds16(bw,        Bg + (size_t)kb * 2);
    gload_lds16(bw + 4096, Bg + rstep + (size_t)kb * 2);
  };

  stage(0, 0);
  asm volatile("s_waitcnt vmcnt(0)" ::: "memory");
  __syncthreads();

#pragma unroll 1
  for (int t = 0; t < NT; ++t) {
    const int cur = t & 1;
    if (t + 1 < NT) stage(cur ^ 1, (t + 1) * 32);
    __builtin_amdgcn_sched_barrier(0);

    bf16x8 af[MI], bfv[4];
#pragma unroll
    for (int i = 0; i < MI; ++i) {
      if constexpr (AF32) {
        const f32x8 v = *(const f32x8*)(AsB + cur * ABUF + (wm + i * 16 + lr) * 128 + lk * 32);
        bf16x8 tt;
#pragma unroll
        for (int e = 0; e < 8; ++e) tt[e] = (bf16)v[e];
        af[i] = tt;
      } else {
        af[i] = *(const bf16x8*)(AsB + cur * ABUF + ((wm + i * 16 + lr) * 32 + lk * 8) * 2);
      }
    }
#pragma unroll
    for (int j = 0; j < 4; ++j)
      bfv[j] = *(const bf16x8*)(BsB + cur * 8192 + ((wn + j * 16 + lr) * 32 + lk * 8) * 2);
#pragma unroll
    for (int i = 0; i < MI; ++i)
#pragma unroll
      for (int j = 0; j < 4; ++j)
        acc[i][j] = __builtin_amdgcn_mfma_f32_16x16x32_bf16(af[i], bfv[j], acc[i][j], 0, 0, 0);

    __syncthreads();
  }

  if constexpr (OUTMODE == 1) {
#pragma unroll
    for (int i = 0; i < MI; ++i)
#pragma unroll
      for (int j = 0; j < 4; ++j) {
        const int n = n0 + wn + j * 16 + lr;
        const float bv = bias[n];
#pragma unroll
        for (int r = 0; r < 4; ++r) {
          const int m = m0 + wm + i * 16 + lk * 4 + r;
          Cf[(size_t)m * Hh + n] = acc[i][j][r] + bv;
        }
      }
  } else {
    const int bidx = m0 >> 11;
    const int kvb  = (m0 & 2047) + wm + lk * 4;
    if (n0 < Hh) {                 // Q -> row-major
#pragma unroll
      for (int i = 0; i < MI; ++i)
#pragma unroll
        for (int j = 0; j < 4; ++j) {
          const int n = n0 + wn + j * 16 + lr;
#pragma unroll
          for (int r = 0; r < 4; ++r) {
            const int m = m0 + wm + i * 16 + lk * 4 + r;
            Qb[(size_t)m * Hh + n] = (bf16)acc[i][j][r];
          }
        }
    } else if (n0 < QKW) {         // K -> Kfrag
#pragma unroll
      for (int i = 0; i < MI; ++i)
#pragma unroll
        for (int j = 0; j < 4; ++j) {
          const int colv = (n0 - Hh) + wn + j * 16 + lr;
          const int hh = colv >> 6, dd = colv & 63;
          bf16* kfh = Kf + (size_t)(bidx * NHh + hh) * 131072;
#pragma unroll
          for (int r = 0; r < 4; ++r) {
            const int kv = kvb + i * 16 + r;
            const size_t idx = (size_t)((((kv >> 5) * 4 + (dd >> 4)) * 64
                                + ((dd >> 3) & 1) * 32 + (kv & 31)) * 8 + (dd & 7));
            kfh[idx] = (bf16)acc[i][j][r];
          }
        }
    } else {                       // V -> Vfrag
#pragma unroll
      for (int i = 0; i < MI; ++i)
#pragma unroll
        for (int j = 0; j < 4; ++j) {
          const int colv = (n0 - QKW) + wn + j * 16 + lr;
          const int hh = colv >> 6, dd = colv & 63;
          const int bh = bidx * NHh + hh;
          const int mb = kvb + i * 16;
          bf16x4 pv;
#pragma unroll
          for (int r = 0; r < 4; ++r) pv[r] = (bf16)acc[i][j][r];
          const size_t idx8 = (((size_t)bh * 128 + (mb >> 4)) * 2 + (dd >> 5)) * 64
                              + ((mb >> 3) & 1) * 32 + (dd & 31);
          *(bf16x4*)(Vf + idx8 * 8 + (mb & 7)) = pv;
        }
    }
  }
}

// Flash attention v10 (r13/r15-proven, 45.9us): Kfrag-linear LDS staging
// (conflict-free lane*16 ds_read_b128), V single-buffered direct from Vfrag,
// counted-vmcnt schedule, cfence-hardened raw s_barrier, 1 barrier/iter.
__global__ __launch_bounds__(256, 3)
void attn_fwd10(const bf16* __restrict__ Qb, const bf16* __restrict__ Kfrag,
                const bf16* __restrict__ Vfrag, bf16* __restrict__ aout)
{
  __shared__ __align__(16) char lds[32768];  // K tiles: grp*16384 + buf*8192 + qh*4096
  const int tid  = threadIdx.x;
  const int wid  = tid >> 6, lane = tid & 63;
  const int lq   = lane & 31, hi = lane >> 5;
  const int qh   = wid & 1, grp = wid >> 1;

  const int orig = blockIdx.x;
  const int swz  = (orig & 7) * 96 + (orig >> 3);
  const int qb   = swz & 31;
  const int bh   = swz >> 5;
  const int b    = bh / NHh, h = bh % NHh;
  const int q0   = qb * 64 + qh * 32;

  constexpr float Cs = 0.18033688011112042f;  // 0.125 * log2(e)
  const bf16* qrow = Qb + (size_t)(b * Ss + q0 + lq) * Hh + h * DHh;
  bf16x8 qf[4];
#pragma unroll
  for (int j = 0; j < 4; ++j) {
    bf16x8 t = *(const bf16x8*)(qrow + j * 16 + hi * 8);
#pragma unroll
    for (int e = 0; e < 8; ++e) t[e] = (bf16)((float)t[e] * Cs);
    qf[j] = t;
  }

  // K staging: fragment-major source, linear LDS dest -- pure memcpy.
  const char* Kfg = (const char*)Kfrag + (size_t)bh * 262144 + grp * 131072 + lane * 16;
  auto stageK = [&](int buf, int it) {
    char* db = lds + grp * 16384 + buf * 8192 + qh * 4096;
    const char* sg = Kfg + (size_t)it * 8192 + qh * 4096;
#pragma unroll
    for (int c = 0; c < 4; ++c)
      gload_lds16(db + c * 1024, sg + c * 1024);
  };

  const char* Vfp = (const char*)Vfrag + (size_t)bh * 262144 + grp * 131072 + lane * 16;

  f32x16 oacc[2] = {};
  f32x16 lacc = {};
  bf16x8 ones;
#pragma unroll
  for (int e = 0; e < 8; ++e) ones[e] = (bf16)1.0f;

  stageK(0, 0);
  asm volatile("s_waitcnt vmcnt(0)" ::: "memory");
  __builtin_amdgcn_sched_barrier(0);

#pragma unroll 1
  for (int i = 0; i < 16; ++i) {
    const int cur = i & 1;

    cfence();                       // nothing sinks below the barrier
    __builtin_amdgcn_s_barrier();   // K(i) from both qh halves visible
    cfence();                       // nothing (esp. stageK) hoists above it

    // V(i) A-fragments, coalesced (oldest in vmcnt order)
    bf16x8 vf[4][2];
    {
      const char* vp = Vfp + (size_t)i * 8192;
#pragma unroll
      for (int s = 0; s < 4; ++s)
#pragma unroll
        for (int dc = 0; dc < 2; ++dc)
          vf[s][dc] = *(const bf16x8*)(vp + (s * 2 + dc) * 1024);
    }

    // prefetch K(i+1) (dummy wrap last iter; drained before merge)
    stageK(cur ^ 1, (i + 1) & 15);
    __builtin_amdgcn_sched_barrier(0);

    // S^T = K * Q^T  -- K frags read linearly at lane*16 (conflict-free)
    f32x16 sacc[2];
    __builtin_amdgcn_s_setprio(1);
#pragma unroll
    for (int kvc = 0; kvc < 2; ++kvc) {
      f32x16 s = {};
      const char* kb = lds + grp * 16384 + cur * 8192 + kvc * 4096 + lane * 16;
#pragma unroll
      for (int j = 0; j < 4; ++j) {
        bf16x8 kf = *(const bf16x8*)(kb + j * 1024);
        s = __builtin_amdgcn_mfma_f32_32x32x16_bf16(kf, qf[j], s, 0, 0, 0);
      }
      sacc[kvc] = s;
    }
    __builtin_amdgcn_s_setprio(0);

    // P = exp2(S) unnormalized; pack to bf16 pairs
    uint32_t w[2][8];
#pragma unroll
    for (int kvc = 0; kvc < 2; ++kvc)
#pragma unroll
      for (int m = 0; m < 8; ++m) {
        union { bf16 hh[2]; uint32_t u; } cv;
        cv.hh[0] = (bf16)fexp2(sacc[kvc][2 * m]);
        cv.hh[1] = (bf16)fexp2(sacc[kvc][2 * m + 1]);
        w[kvc][m] = cv.u;
      }

    // V(i) retired (8 oldest); K-prefetch (4 newest) may stay in flight
    asm volatile("s_waitcnt vmcnt(4)" ::: "memory");
    __builtin_amdgcn_sched_barrier(0);

    // build P^T B-fragments via permlane32_swap; accumulate O^T, l
    __builtin_amdgcn_s_setprio(1);
#pragma unroll
    for (int s = 0; s < 4; ++s) {
      const int kvc = s >> 1, sb = s & 1;
      uint32_t a0 = w[kvc][4 * sb + 0], b0 = w[kvc][4 * sb + 2];
      uint32_t a1 = w[kvc][4 * sb + 1], b1 = w[kvc][4 * sb + 3];
      asm("v_permlane32_swap_b32 %0, %1" : "+v"(a0), "+v"(b0));
      asm("v_permlane32_swap_b32 %0, %1" : "+v"(a1), "+v"(b1));
      union { uint32_t u[4]; bf16x8 v; } pf;
      pf.u[0] = a0; pf.u[1] = a1; pf.u[2] = b0; pf.u[3] = b1;
#pragma unroll
      for (int dc = 0; dc < 2; ++dc)
        oacc[dc] = __builtin_amdgcn_mfma_f32_32x32x16_bf16(vf[s][dc], pf.v, oacc[dc], 0, 0, 0);
      lacc = __builtin_amdgcn_mfma_f32_32x32x16_bf16(ones, pf.v, lacc, 0, 0, 0);
    }
    __builtin_amdgcn_s_setprio(0);

    // my K-prefetch landed; barrier at next iter top syncs both qh halves
    asm volatile("s_waitcnt vmcnt(0)" ::: "memory");
    __builtin_amdgcn_sched_barrier(0);
  }

  __syncthreads();  // protect K-buffer region before merge-buffer reuse

  // merge kv-halves by summation: grp1 exports (O, l) via LDS, grp0 combines
  if (grp == 1) {
    char* mb = lds + qh * 8704;
#pragma unroll
    for (int dc = 0; dc < 2; ++dc)
#pragma unroll
      for (int rr = 0; rr < 4; ++rr) {
        f32x4 t;
#pragma unroll
        for (int e = 0; e < 4; ++e) t[e] = oacc[dc][rr * 4 + e];
        *(f32x4*)(mb + (dc * 4 + rr) * 1024 + lane * 16) = t;
      }
    *(float*)(mb + 8192 + lane * 4) = lacc[0];
  }
  __syncthreads();
  if (grp == 0) {
    const char* mb = lds + qh * 8704;
    const float l2 = *(const float*)(mb + 8192 + lane * 4);
    const float linv = 1.0f / (lacc[0] + l2);
    bf16* orow = aout + (size_t)(b * Ss + q0 + lq) * Hh + h * DHh;
#pragma unroll
    for (int dc = 0; dc < 2; ++dc)
#pragma unroll
      for (int rr = 0; rr < 4; ++rr) {
        const f32x4 o2 = *(const f32x4*)(mb + (dc * 4 + rr) * 1024 + lane * 16);
        bf16x4 ov;
#pragma unroll
        for (int e = 0; e < 4; ++e)
          ov[e] = (bf16)((oacc[dc][rr * 4 + e] + o2[e]) * linv);
        *(bf16x4*)(orow + dc * 32 + rr * 8 + hi * 4) = ov;
      }
  }
}

extern "C" void kernel_launch(void* const* d_in, const int* in_sizes, int n_in,
                              void* d_out, int out_size, void* d_ws, size_t ws_size,
                              hipStream_t stream) {
  const float* x     = (const float*)d_in[0];
  const float* w_qkv = (const float*)d_in[1];
  const float* w_out = (const float*)d_in[2];
  const float* b_out = (const float*)d_in[3];
  char* ws = (char*)d_ws;
  bf16* wqkvb = (bf16*)(ws + 6291456);
  bf16* woutb = (bf16*)(ws + 9830400);
  bf16* Qb    = (bf16*)(ws + 11010048);
  bf16* Kfrag = (bf16*)(ws + 17301504);
  bf16* Vfrag = (bf16*)(ws + 23592960);
  bf16* aoutb = (bf16*)(ws + 29884416);

  cvt2_f32_bf16<<<576, 256, 0, stream>>>(w_qkv, wqkvb, w_out, woutb);

  // GEMM1 reads x directly as f32 (AF32=1) -- cvt of x fused into staging
  gemm_bt<0, 128, 18, 1><<<576, 256, 0, stream>>>((const bf16*)x, wqkvb, Qb, Kfrag, Vfrag,
                                                  nullptr, nullptr);
  attn_fwd10<<<768, 256, 0, stream>>>(Qb, Kfrag, Vfrag, aoutb);
  gemm_bt<1, 64, 6, 0><<<384, 256, 0, stream>>>(aoutb, woutb, nullptr, nullptr, nullptr,
                                                (float*)d_out, b_out);
}

// Round 18
// 85.323 us; speedup vs baseline: 1.2625x; 1.0933x over previous
//
#include <hip/hip_runtime.h>
#include <cstdint>
#include <cstddef>

typedef __bf16 bf16;
typedef __bf16 bf16x8 __attribute__((ext_vector_type(8)));
typedef __bf16 bf16x4 __attribute__((ext_vector_type(4)));
typedef float  f32x4  __attribute__((ext_vector_type(4)));
typedef float  f32x16 __attribute__((ext_vector_type(16)));

constexpr int Bb  = 2;
constexpr int Ss  = 2048;
constexpr int Hh  = 768;
constexpr int NHh = 12;
constexpr int DHh = 64;
constexpr int Mm  = Bb * Ss;   // 4096
constexpr int N3  = 3 * Hh;    // 2304
constexpr int QKW = 2 * Hh;    // 1536

__device__ __forceinline__ float fexp2(float x) { return __builtin_amdgcn_exp2f(x); }

__device__ __forceinline__ void gload_lds16(void* lds, const void* g) {
  __builtin_amdgcn_global_load_lds(
      (__attribute__((address_space(1))) void*)(uintptr_t)g,
      (__attribute__((address_space(3))) void*)(uint32_t)(uintptr_t)lds,
      16, 0, 0);
}

// compiler-only memory fence: emits nothing, pins memory-op ordering (r12-proven)
__device__ __forceinline__ void cfence() { asm volatile("" ::: "memory"); }

// single kernel converts all three f32 inputs to bf16
__global__ void cvt3_f32_bf16(const float* __restrict__ x,  bf16* __restrict__ xb,
                              const float* __restrict__ w1, bf16* __restrict__ w1b,
                              const float* __restrict__ w2, bf16* __restrict__ w2b) {
  const int st = gridDim.x * blockDim.x;
  int i0 = blockIdx.x * blockDim.x + threadIdx.x;
  for (int i = i0; i < 786432; i += st) {
    float4 v = ((const float4*)x)[i];
    bf16x4 o; o[0]=(bf16)v.x; o[1]=(bf16)v.y; o[2]=(bf16)v.z; o[3]=(bf16)v.w;
    ((bf16x4*)xb)[i] = o;
  }
  for (int i = i0; i < 442368; i += st) {
    float4 v = ((const float4*)w1)[i];
    bf16x4 o; o[0]=(bf16)v.x; o[1]=(bf16)v.y; o[2]=(bf16)v.z; o[3]=(bf16)v.w;
    ((bf16x4*)w1b)[i] = o;
  }
  for (int i = i0; i < 147456; i += st) {
    float4 v = ((const float4*)w2)[i];
    bf16x4 o; o[0]=(bf16)v.x; o[1]=(bf16)v.y; o[2]=(bf16)v.z; o[3]=(bf16)v.w;
    ((bf16x4*)w2b)[i] = o;
  }
}

// C = A[M,768] * Bw[N,768]^T, tile BM x 128, double-buffered LDS, 1 barrier/iter.
// 1D grid, XCD-swizzled m-chunked (T1): each XCD owns contiguous m-rows ->
// A-panel reuse is XCD-L2-local. NXT = N/128 tiles.
// OUTMODE 0 (BM=128): Q -> row-major [4096][768]; K -> Kfrag, V -> Vfrag
// (MFMA-A-fragment order, proven r9/r13). OUTMODE 1: f32 out + bias.
template<int OUTMODE, int BM, int NXT>
__global__ __launch_bounds__(256, 3)
void gemm_bt(const bf16* __restrict__ A, const bf16* __restrict__ Bw,
             bf16* __restrict__ Qb, bf16* __restrict__ Kf, bf16* __restrict__ Vf,
             float* __restrict__ Cf, const float* __restrict__ bias)
{
  constexpr int K = 768;
  constexpr int NT = K / 32;
  constexpr int MI = BM / 32;
  constexpr int ABUF = BM * 64;
  __shared__ bf16 As[2][BM * 32];
  __shared__ bf16 Bs[2][128 * 32];
  const int tid  = threadIdx.x;
  const int wid  = tid >> 6, lane = tid & 63;
  const int lr   = lane & 15, lk = lane >> 4;

  // XCD swizzle (grid % 8 == 0): each XCD gets a contiguous chunk of m-rows
  const int id   = blockIdx.x;
  const int swz  = (id & 7) * (gridDim.x >> 3) + (id >> 3);
  const int n0   = (swz % NXT) * 128;
  const int m0   = (swz / NXT) * BM;
  const int wm   = (wid >> 1) * (BM / 2), wn = (wid & 1) * 64;

  f32x4 acc[MI][4] = {};

  const char* Ag = (const char*)(A  + (size_t)m0 * K) + (size_t)(tid >> 2) * (K * 2) + (tid & 3) * 16;
  const char* Bg = (const char*)(Bw + (size_t)n0 * K) + (size_t)(tid >> 2) * (K * 2) + (tid & 3) * 16;
  constexpr size_t rstep = (size_t)64 * K * 2;

  auto stage = [&](int buf, int kb) {
    char* aw = (char*)As + buf * ABUF + wid * 1024;
    char* bw = (char*)Bs + buf * 8192 + wid * 1024;
    gload_lds16(aw, Ag + (size_t)kb * 2);
    if constexpr (BM == 128)
      gload_lds16(aw + 4096, Ag + rstep + (size_t)kb * 2);
    gload_lds16(bw,        Bg + (size_t)kb * 2);
    gload_lds16(bw + 4096, Bg + rstep + (size_t)kb * 2);
  };

  stage(0, 0);
  asm volatile("s_waitcnt vmcnt(0)" ::: "memory");
  __syncthreads();

#pragma unroll 1
  for (int t = 0; t < NT; ++t) {
    const int cur = t & 1;
    if (t + 1 < NT) stage(cur ^ 1, (t + 1) * 32);
    __builtin_amdgcn_sched_barrier(0);

    bf16x8 af[MI], bfv[4];
#pragma unroll
    for (int i = 0; i < MI; ++i)
      af[i]  = *(const bf16x8*)((const char*)As + cur * ABUF + ((wm + i * 16 + lr) * 32 + lk * 8) * 2);
#pragma unroll
    for (int j = 0; j < 4; ++j)
      bfv[j] = *(const bf16x8*)((const char*)Bs + cur * 8192 + ((wn + j * 16 + lr) * 32 + lk * 8) * 2);
#pragma unroll
    for (int i = 0; i < MI; ++i)
#pragma unroll
      for (int j = 0; j < 4; ++j)
        acc[i][j] = __builtin_amdgcn_mfma_f32_16x16x32_bf16(af[i], bfv[j], acc[i][j], 0, 0, 0);

    __syncthreads();
  }

  if constexpr (OUTMODE == 1) {
#pragma unroll
    for (int i = 0; i < MI; ++i)
#pragma unroll
      for (int j = 0; j < 4; ++j) {
        const int n = n0 + wn + j * 16 + lr;
        const float bv = bias[n];
#pragma unroll
        for (int r = 0; r < 4; ++r) {
          const int m = m0 + wm + i * 16 + lk * 4 + r;
          Cf[(size_t)m * Hh + n] = acc[i][j][r] + bv;
        }
      }
  } else {
    const int bidx = m0 >> 11;
    const int kvb  = (m0 & 2047) + wm + lk * 4;
    if (n0 < Hh) {                 // Q -> row-major
#pragma unroll
      for (int i = 0; i < MI; ++i)
#pragma unroll
        for (int j = 0; j < 4; ++j) {
          const int n = n0 + wn + j * 16 + lr;
#pragma unroll
          for (int r = 0; r < 4; ++r) {
            const int m = m0 + wm + i * 16 + lk * 4 + r;
            Qb[(size_t)m * Hh + n] = (bf16)acc[i][j][r];
          }
        }
    } else if (n0 < QKW) {         // K -> Kfrag
#pragma unroll
      for (int i = 0; i < MI; ++i)
#pragma unroll
        for (int j = 0; j < 4; ++j) {
          const int colv = (n0 - Hh) + wn + j * 16 + lr;
          const int hh = colv >> 6, dd = colv & 63;
          bf16* kfh = Kf + (size_t)(bidx * NHh + hh) * 131072;
#pragma unroll
          for (int r = 0; r < 4; ++r) {
            const int kv = kvb + i * 16 + r;
            const size_t idx = (size_t)((((kv >> 5) * 4 + (dd >> 4)) * 64
                                + ((dd >> 3) & 1) * 32 + (kv & 31)) * 8 + (dd & 7));
            kfh[idx] = (bf16)acc[i][j][r];
          }
        }
    } else {                       // V -> Vfrag
#pragma unroll
      for (int i = 0; i < MI; ++i)
#pragma unroll
        for (int j = 0; j < 4; ++j) {
          const int colv = (n0 - QKW) + wn + j * 16 + lr;
          const int hh = colv >> 6, dd = colv & 63;
          const int bh = bidx * NHh + hh;
          const int mb = kvb + i * 16;
          bf16x4 pv;
#pragma unroll
          for (int r = 0; r < 4; ++r) pv[r] = (bf16)acc[i][j][r];
          const size_t idx8 = (((size_t)bh * 128 + (mb >> 4)) * 2 + (dd >> 5)) * 64
                              + ((mb >> 3) & 1) * 32 + (dd & 31);
          *(bf16x4*)(Vf + idx8 * 8 + (mb & 7)) = pv;
        }
    }
  }
}

// Flash attention v10 (r13-proven, 46.2us): Kfrag-linear LDS staging
// (conflict-free lane*16 ds_read_b128), V single-buffered direct from Vfrag,
// counted-vmcnt schedule, cfence-hardened raw s_barrier, 1 barrier/iter.
__global__ __launch_bounds__(256, 3)
void attn_fwd10(const bf16* __restrict__ Qb, const bf16* __restrict__ Kfrag,
                const bf16* __restrict__ Vfrag, bf16* __restrict__ aout)
{
  __shared__ __align__(16) char lds[32768];  // K tiles: grp*16384 + buf*8192 + qh*4096
  const int tid  = threadIdx.x;
  const int wid  = tid >> 6, lane = tid & 63;
  const int lq   = lane & 31, hi = lane >> 5;
  const int qh   = wid & 1, grp = wid >> 1;

  const int orig = blockIdx.x;
  const int swz  = (orig & 7) * 96 + (orig >> 3);
  const int qb   = swz & 31;
  const int bh   = swz >> 5;
  const int b    = bh / NHh, h = bh % NHh;
  const int q0   = qb * 64 + qh * 32;

  constexpr float Cs = 0.18033688011112042f;  // 0.125 * log2(e)
  const bf16* qrow = Qb + (size_t)(b * Ss + q0 + lq) * Hh + h * DHh;
  bf16x8 qf[4];
#pragma unroll
  for (int j = 0; j < 4; ++j) {
    bf16x8 t = *(const bf16x8*)(qrow + j * 16 + hi * 8);
#pragma unroll
    for (int e = 0; e < 8; ++e) t[e] = (bf16)((float)t[e] * Cs);
    qf[j] = t;
  }

  // K staging: fragment-major source, linear LDS dest -- pure memcpy.
  const char* Kfg = (const char*)Kfrag + (size_t)bh * 262144 + grp * 131072 + lane * 16;
  auto stageK = [&](int buf, int it) {
    char* db = lds + grp * 16384 + buf * 8192 + qh * 4096;
    const char* sg = Kfg + (size_t)it * 8192 + qh * 4096;
#pragma unroll
    for (int c = 0; c < 4; ++c)
      gload_lds16(db + c * 1024, sg + c * 1024);
  };

  const char* Vfp = (const char*)Vfrag + (size_t)bh * 262144 + grp * 131072 + lane * 16;

  f32x16 oacc[2] = {};
  f32x16 lacc = {};
  bf16x8 ones;
#pragma unroll
  for (int e = 0; e < 8; ++e) ones[e] = (bf16)1.0f;

  stageK(0, 0);
  asm volatile("s_waitcnt vmcnt(0)" ::: "memory");
  __builtin_amdgcn_sched_barrier(0);

#pragma unroll 1
  for (int i = 0; i < 16; ++i) {
    const int cur = i & 1;

    cfence();                       // nothing sinks below the barrier
    __builtin_amdgcn_s_barrier();   // K(i) from both qh halves visible
    cfence();                       // nothing (esp. stageK) hoists above it

    // V(i) A-fragments, coalesced (oldest in vmcnt order)
    bf16x8 vf[4][2];
    {
      const char* vp = Vfp + (size_t)i * 8192;
#pragma unroll
      for (int s = 0; s < 4; ++s)
#pragma unroll
        for (int dc = 0; dc < 2; ++dc)
          vf[s][dc] = *(const bf16x8*)(vp + (s * 2 + dc) * 1024);
    }

    // prefetch K(i+1) (dummy wrap last iter; drained before merge)
    stageK(cur ^ 1, (i + 1) & 15);
    __builtin_amdgcn_sched_barrier(0);

    // S^T = K * Q^T  -- K frags read linearly at lane*16 (conflict-free)
    f32x16 sacc[2];
    __builtin_amdgcn_s_setprio(1);
#pragma unroll
    for (int kvc = 0; kvc < 2; ++kvc) {
      f32x16 s = {};
      const char* kb = lds + grp * 16384 + cur * 8192 + kvc * 4096 + lane * 16;
#pragma unroll
      for (int j = 0; j < 4; ++j) {
        bf16x8 kf = *(const bf16x8*)(kb + j * 1024);
        s = __builtin_amdgcn_mfma_f32_32x32x16_bf16(kf, qf[j], s, 0, 0, 0);
      }
      sacc[kvc] = s;
    }
    __builtin_amdgcn_s_setprio(0);

    // P = exp2(S) unnormalized; pack to bf16 pairs
    uint32_t w[2][8];
#pragma unroll
    for (int kvc = 0; kvc < 2; ++kvc)
#pragma unroll
      for (int m = 0; m < 8; ++m) {
        union { bf16 hh[2]; uint32_t u; } cv;
        cv.hh[0] = (bf16)fexp2(sacc[kvc][2 * m]);
        cv.hh[1] = (bf16)fexp2(sacc[kvc][2 * m + 1]);
        w[kvc][m] = cv.u;
      }

    // V(i) retired (8 oldest); K-prefetch (4 newest) may stay in flight
    asm volatile("s_waitcnt vmcnt(4)" ::: "memory");
    __builtin_amdgcn_sched_barrier(0);

    // build P^T B-fragments via permlane32_swap; accumulate O^T, l
    __builtin_amdgcn_s_setprio(1);
#pragma unroll
    for (int s = 0; s < 4; ++s) {
      const int kvc = s >> 1, sb = s & 1;
      uint32_t a0 = w[kvc][4 * sb + 0], b0 = w[kvc][4 * sb + 2];
      uint32_t a1 = w[kvc][4 * sb + 1], b1 = w[kvc][4 * sb + 3];
      asm("v_permlane32_swap_b32 %0, %1" : "+v"(a0), "+v"(b0));
      asm("v_permlane32_swap_b32 %0, %1" : "+v"(a1), "+v"(b1));
      union { uint32_t u[4]; bf16x8 v; } pf;
      pf.u[0] = a0; pf.u[1] = a1; pf.u[2] = b0; pf.u[3] = b1;
#pragma unroll
      for (int dc = 0; dc < 2; ++dc)
        oacc[dc] = __builtin_amdgcn_mfma_f32_32x32x16_bf16(vf[s][dc], pf.v, oacc[dc], 0, 0, 0);
      lacc = __builtin_amdgcn_mfma_f32_32x32x16_bf16(ones, pf.v, lacc, 0, 0, 0);
    }
    __builtin_amdgcn_s_setprio(0);

    // my K-prefetch landed; barrier at next iter top syncs both qh halves
    asm volatile("s_waitcnt vmcnt(0)" ::: "memory");
    __builtin_amdgcn_sched_barrier(0);
  }

  __syncthreads();  // protect K-buffer region before merge-buffer reuse

  // merge kv-halves by summation: grp1 exports (O, l) via LDS, grp0 combines
  if (grp == 1) {
    char* mb = lds + qh * 8704;
#pragma unroll
    for (int dc = 0; dc < 2; ++dc)
#pragma unroll
      for (int rr = 0; rr < 4; ++rr) {
        f32x4 t;
#pragma unroll
        for (int e = 0; e < 4; ++e) t[e] = oacc[dc][rr * 4 + e];
        *(f32x4*)(mb + (dc * 4 + rr) * 1024 + lane * 16) = t;
      }
    *(float*)(mb + 8192 + lane * 4) = lacc[0];
  }
  __syncthreads();
  if (grp == 0) {
    const char* mb = lds + qh * 8704;
    const float l2 = *(const float*)(mb + 8192 + lane * 4);
    const float linv = 1.0f / (lacc[0] + l2);
    bf16* orow = aout + (size_t)(b * Ss + q0 + lq) * Hh + h * DHh;
#pragma unroll
    for (int dc = 0; dc < 2; ++dc)
#pragma unroll
      for (int rr = 0; rr < 4; ++rr) {
        const f32x4 o2 = *(const f32x4*)(mb + (dc * 4 + rr) * 1024 + lane * 16);
        bf16x4 ov;
#pragma unroll
        for (int e = 0; e < 4; ++e)
          ov[e] = (bf16)((oacc[dc][rr * 4 + e] + o2[e]) * linv);
        *(bf16x4*)(orow + dc * 32 + rr * 8 + hi * 4) = ov;
      }
  }
}

extern "C" void kernel_launch(void* const* d_in, const int* in_sizes, int n_in,
                              void* d_out, int out_size, void* d_ws, size_t ws_size,
                              hipStream_t stream) {
  const float* x     = (const float*)d_in[0];
  const float* w_qkv = (const float*)d_in[1];
  const float* w_out = (const float*)d_in[2];
  const float* b_out = (const float*)d_in[3];
  char* ws = (char*)d_ws;
  bf16* xb    = (bf16*)(ws + 0);
  bf16* wqkvb = (bf16*)(ws + 6291456);
  bf16* woutb = (bf16*)(ws + 9830400);
  bf16* Qb    = (bf16*)(ws + 11010048);
  bf16* Kfrag = (bf16*)(ws + 17301504);
  bf16* Vfrag = (bf16*)(ws + 23592960);
  bf16* aoutb = (bf16*)(ws + 29884416);

  cvt3_f32_bf16<<<2048, 256, 0, stream>>>(x, xb, w_qkv, wqkvb, w_out, woutb);

  gemm_bt<0, 128, 18><<<576, 256, 0, stream>>>(xb, wqkvb, Qb, Kfrag, Vfrag,
                                               nullptr, nullptr);
  attn_fwd10<<<768, 256, 0, stream>>>(Qb, Kfrag, Vfrag, aoutb);
  gemm_bt<1, 64, 6><<<384, 256, 0, stream>>>(aoutb, woutb, nullptr, nullptr, nullptr,
                                             (float*)d_out, b_out);
}